// Round 14
// baseline (110.390 us; speedup 1.0000x reference)
//
#include <hip/hip_runtime.h>
#include <stdint.h>

#define T_TOKENS 8192
#define K_DIM    4096
#define NEXP     64
#define TB       128            // tokens per block: 4 rowgroups x 32 rows

typedef short bf16x8 __attribute__((ext_vector_type(8)));
typedef float f32x4  __attribute__((ext_vector_type(4)));

__device__ __forceinline__ uint32_t f2bf(float v) {
    uint32_t u = __builtin_bit_cast(uint32_t, v);
    return (u + 0x7fffu + ((u >> 16) & 1u)) >> 16;
}
__device__ __forceinline__ float bf2f(uint32_t b) {
    return __builtin_bit_cast(float, b << 16);
}
struct S3 { short h, l, q; };
__device__ __forceinline__ S3 cvt1(float v) {
    uint32_t hb = f2bf(v); float r  = v - bf2f(hb);
    uint32_t lb = f2bf(r); float r2 = r - bf2f(lb);
    uint32_t qb = f2bf(r2);
    S3 o; o.h = (short)hb; o.l = (short)lb; o.q = (short)qb; return o;
}
__device__ __forceinline__ void cvt8(const float4 a0, const float4 a1,
                                     bf16x8& xh, bf16x8& xl, bf16x8& xq) {
    const float av[8] = {a0.x, a0.y, a0.z, a0.w, a1.x, a1.y, a1.z, a1.w};
#pragma unroll
    for (int j = 0; j < 8; ++j) {
        S3 o = cvt1(av[j]);
        xh[j] = o.h; xl[j] = o.l; xq[j] = o.q;
    }
}

// ---------- kernel 0: W [64][4096] fp32 -> fragment-ordered bf16 terms -------
// Wf layout (float4 = bf16x8): [kstep 128][etile 4][term 3][lane 64]
__global__ void wpack(const float* __restrict__ W, float4* __restrict__ Wf,
                      float* __restrict__ out_counts) {
    const int l     = threadIdx.x;
    const int kstep = blockIdx.x;
    const int etile = blockIdx.y;
    if (kstep == 0 && etile == 0)
        out_counts[l] = 0.f;             // stream-ordered before router_finish
    const int e = etile * 16 + (l & 15);
    const int k = kstep * 32 + (l >> 4) * 8;
    const float* src = W + (size_t)e * K_DIM + k;
    bf16x8 h, l1, l2;
#pragma unroll
    for (int j = 0; j < 8; ++j) {
        S3 o = cvt1(src[j]);
        h[j] = o.h; l1[j] = o.l; l2[j] = o.q;
    }
    const size_t base = ((size_t)(kstep * 4 + etile) * 3) * 64 + l;
    Wf[base]       = __builtin_bit_cast(float4, h);
    Wf[base + 64]  = __builtin_bit_cast(float4, l1);
    Wf[base + 128] = __builtin_bit_cast(float4, l2);
}

// ---------- kernel 1: WAVE-AUTONOMOUS split-K GEMM — no LDS, no barriers -----
// Each wave: 32 token-rows x 32 experts x K-slice, fully independent.
// x and B fragments load per-lane into 3-slot rotated register sets, 16-kstep
// loop fully unrolled (static indices). 10 loads for ks+2 issue while ks
// computes -> ~20 f4/thread (~164 KB/CU) in flight, waves free-run like the
// R12 probes (which hit 6.2 TB/s on this exact x pattern).
template <int NCH>
__global__ __launch_bounds__(512, 2) void gemm_mfma(
    const float*  __restrict__ x,
    const float4* __restrict__ Wf,
    float* __restrict__ P)          // [S][8192][64]
{
    const int tid  = threadIdx.x;
    const int l    = tid & 63;
    const int wv   = __builtin_amdgcn_readfirstlane(tid >> 6);
    const int rg   = wv >> 1;            // rowgroup 0..3  (32 rows each)
    const int cg   = wv & 1;             // colgroup 0..1  (32 experts each)
    const int slice = blockIdx.x;        // grid.x = S  -> id%8 = slice -> XCD
    const int t0    = blockIdx.y * TB;
    const int k0    = slice * (NCH * 32);

    const float4* x4 = (const float4*)x;
    const size_t xr0 = (size_t)(t0 + rg * 32 + (l & 15)) * (K_DIM / 4)
                     + (size_t)(k0 >> 2) + ((l >> 4) * 2);
    const size_t xr1 = xr0 + (size_t)16 * (K_DIM / 4);
    // B base: etile cg*2, term 0, this lane; kstep stride = 4*3*64 = 768 f4
    const float4* bb = Wf + (((size_t)(k0 >> 5) * 4 + cg * 2) * 3) * 64 + l;

    f32x4 acc00 = {0,0,0,0}, acc01 = {0,0,0,0};   // [et][rowtile]
    f32x4 acc10 = {0,0,0,0}, acc11 = {0,0,0,0};

    float4 xs[3][4];    // [slot][{r0k0,r0k1,r1k0,r1k1}]
    float4 bs[3][6];    // [slot][{e0t0,e0t1,e0t2,e1t0,e1t1,e1t2}]

#define LOADK(ks, slot)                                                        \
    do {                                                                       \
        const size_t xo = (size_t)(ks) * 8;                                    \
        xs[slot][0] = x4[xr0 + xo];     xs[slot][1] = x4[xr0 + xo + 1];        \
        xs[slot][2] = x4[xr1 + xo];     xs[slot][3] = x4[xr1 + xo + 1];        \
        const float4* bp = bb + (size_t)(ks) * 768;                            \
        bs[slot][0] = bp[0];   bs[slot][1] = bp[64];  bs[slot][2] = bp[128];   \
        bs[slot][3] = bp[192]; bs[slot][4] = bp[256]; bs[slot][5] = bp[320];   \
    } while (0)

    LOADK(0, 0);
    LOADK(1, 1);

#pragma unroll
    for (int ks = 0; ks < NCH; ++ks) {
        if (ks + 2 < NCH) LOADK(ks + 2, (ks + 2) % 3);
        const int s = ks % 3;

        bf16x8 xh0, xl0, xq0, xh1, xl1, xq1;
        cvt8(xs[s][0], xs[s][1], xh0, xl0, xq0);   // rowtile 0
        cvt8(xs[s][2], xs[s][3], xh1, xl1, xq1);   // rowtile 1

#pragma unroll
        for (int e = 0; e < 2; ++e) {
            bf16x8 wh = __builtin_bit_cast(bf16x8, bs[s][e * 3 + 0]);
            bf16x8 wl = __builtin_bit_cast(bf16x8, bs[s][e * 3 + 1]);
            bf16x8 wq = __builtin_bit_cast(bf16x8, bs[s][e * 3 + 2]);
            f32x4& a0 = e ? acc10 : acc00;
            f32x4& a1 = e ? acc11 : acc01;
            a0 = __builtin_amdgcn_mfma_f32_16x16x32_bf16(xh0, wh, a0, 0, 0, 0);
            a0 = __builtin_amdgcn_mfma_f32_16x16x32_bf16(xh0, wl, a0, 0, 0, 0);
            a0 = __builtin_amdgcn_mfma_f32_16x16x32_bf16(xh0, wq, a0, 0, 0, 0);
            a0 = __builtin_amdgcn_mfma_f32_16x16x32_bf16(xl0, wh, a0, 0, 0, 0);
            a0 = __builtin_amdgcn_mfma_f32_16x16x32_bf16(xl0, wl, a0, 0, 0, 0);
            a0 = __builtin_amdgcn_mfma_f32_16x16x32_bf16(xq0, wh, a0, 0, 0, 0);
            a1 = __builtin_amdgcn_mfma_f32_16x16x32_bf16(xh1, wh, a1, 0, 0, 0);
            a1 = __builtin_amdgcn_mfma_f32_16x16x32_bf16(xh1, wl, a1, 0, 0, 0);
            a1 = __builtin_amdgcn_mfma_f32_16x16x32_bf16(xh1, wq, a1, 0, 0, 0);
            a1 = __builtin_amdgcn_mfma_f32_16x16x32_bf16(xl1, wh, a1, 0, 0, 0);
            a1 = __builtin_amdgcn_mfma_f32_16x16x32_bf16(xl1, wl, a1, 0, 0, 0);
            a1 = __builtin_amdgcn_mfma_f32_16x16x32_bf16(xq1, wh, a1, 0, 0, 0);
        }
    }
#undef LOADK

    // epilogue: C/D map col=lane&15 (expert-within-etile), row=(lane>>4)*4+i
    float* Pp = P + (size_t)slice * T_TOKENS * NEXP;
#pragma unroll
    for (int e = 0; e < 2; ++e) {
#pragma unroll
        for (int rt = 0; rt < 2; ++rt) {
            const f32x4 a = e ? (rt ? acc11 : acc10) : (rt ? acc01 : acc00);
            const int ecol = (cg * 2 + e) * 16 + (l & 15);
#pragma unroll
            for (int i = 0; i < 4; ++i) {
                int t = t0 + rg * 32 + rt * 16 + (l >> 4) * 4 + i;
                Pp[(size_t)t * NEXP + ecol] = a[i];
            }
        }
    }
}

// ---------- kernel 2: reduce slices + softmax + argmax + bincount ------------
template <int S>
__global__ __launch_bounds__(256) void router_finish_t(
    const float* __restrict__ P, float* __restrict__ out)
{
    const int lane = threadIdx.x & 63;   // expert
    const int wv   = threadIdx.x >> 6;
    const int t    = blockIdx.x * 4 + wv;

    float lg = 0.f;
#pragma unroll
    for (int s = 0; s < S; ++s)
        lg += P[((size_t)s * T_TOKENS + t) * NEXP + lane];

    float* out_w = out;
    float* out_i = out + T_TOKENS;
    float* out_s = out + 2 * T_TOKENS;
    float* out_c = out + 2 * T_TOKENS + (size_t)T_TOKENS * NEXP;

    float m = lg;
#pragma unroll
    for (int off = 32; off > 0; off >>= 1)
        m = fmaxf(m, __shfl_xor(m, off));
    float p = expf(lg - m);
    float s = p;
#pragma unroll
    for (int off = 32; off > 0; off >>= 1)
        s += __shfl_xor(s, off);
    float sc = p / s;

    float bv = sc; int bi = lane;
#pragma unroll
    for (int off = 32; off > 0; off >>= 1) {
        float ov = __shfl_xor(bv, off);
        int   oi = __shfl_xor(bi, off);
        if (ov > bv || (ov == bv && oi < bi)) { bv = ov; bi = oi; }
    }
    out_s[(size_t)t * NEXP + lane] = sc;
    if (lane == 0) {
        out_w[t] = bv;
        out_i[t] = (float)bi;
        atomicAdd(&out_c[bi], 1.0f);   // counts zeroed by wpack this call
    }
}

extern "C" void kernel_launch(void* const* d_in, const int* in_sizes, int n_in,
                              void* d_out, int out_size, void* d_ws, size_t ws_size,
                              hipStream_t stream)
{
    const float* x = (const float*)d_in[0];
    const float* W = (const float*)d_in[1];
    float* out = (float*)d_out;
    float* out_s = out + 2 * T_TOKENS;
    float* out_c = out + 2 * T_TOKENS + (size_t)T_TOKENS * NEXP;

    const size_t wf_bytes  = (size_t)128 * 4 * 3 * 64 * 16;           // 1.5 MiB
    const size_t per_slice = (size_t)T_TOKENS * NEXP * sizeof(float); // 2 MiB

    int S = 8;
    while (S > 1 && wf_bytes + (size_t)S * per_slice > ws_size) S >>= 1;
    float4* Wf = (float4*)d_ws;
    float* Pbuf;
    if (wf_bytes + per_slice <= ws_size) {
        Pbuf = (float*)((char*)d_ws + wf_bytes);
    } else {
        S = 1;
        Pbuf = out_s;
    }

    wpack<<<dim3(128, 4), 64, 0, stream>>>(W, Wf, out_c);
    // grid.x = S (slice) so linear block id % 8 == slice -> slice->XCD affinity
    switch (S) {
        case 8: gemm_mfma<16> <<<dim3(8, T_TOKENS / TB), 512, 0, stream>>>(x, Wf, Pbuf); break;
        case 4: gemm_mfma<32> <<<dim3(4, T_TOKENS / TB), 512, 0, stream>>>(x, Wf, Pbuf); break;
        case 2: gemm_mfma<64> <<<dim3(2, T_TOKENS / TB), 512, 0, stream>>>(x, Wf, Pbuf); break;
        default: gemm_mfma<128><<<dim3(1, T_TOKENS / TB), 512, 0, stream>>>(x, Wf, Pbuf); break;
    }
    switch (S) {
        case 8: router_finish_t<8><<<T_TOKENS / 4, 256, 0, stream>>>(Pbuf, out); break;
        case 4: router_finish_t<4><<<T_TOKENS / 4, 256, 0, stream>>>(Pbuf, out); break;
        case 2: router_finish_t<2><<<T_TOKENS / 4, 256, 0, stream>>>(Pbuf, out); break;
        default: router_finish_t<1><<<T_TOKENS / 4, 256, 0, stream>>>(Pbuf, out); break;
    }
}

// Round 15
// 109.733 us; speedup vs baseline: 1.0060x; 1.0060x over previous
//
#include <hip/hip_runtime.h>
#include <stdint.h>

#define T_TOKENS 8192
#define K_DIM    4096
#define NEXP     64
#define TB       128            // tokens per block (8 waves x 16 rows)

typedef short bf16x8 __attribute__((ext_vector_type(8)));
typedef float f32x4  __attribute__((ext_vector_type(4)));

__device__ __forceinline__ uint32_t f2bf(float v) {
    uint32_t u = __builtin_bit_cast(uint32_t, v);
    return (u + 0x7fffu + ((u >> 16) & 1u)) >> 16;
}
__device__ __forceinline__ float bf2f(uint32_t b) {
    return __builtin_bit_cast(float, b << 16);
}
struct S3 { short h, l, q; };
__device__ __forceinline__ S3 cvt1(float v) {
    uint32_t hb = f2bf(v); float r  = v - bf2f(hb);
    uint32_t lb = f2bf(r); float r2 = r - bf2f(lb);
    uint32_t qb = f2bf(r2);
    S3 o; o.h = (short)hb; o.l = (short)lb; o.q = (short)qb; return o;
}
__device__ __forceinline__ void cvt8(const float4 a0, const float4 a1,
                                     bf16x8& xh, bf16x8& xl, bf16x8& xq) {
    const float av[8] = {a0.x, a0.y, a0.z, a0.w, a1.x, a1.y, a1.z, a1.w};
#pragma unroll
    for (int j = 0; j < 8; ++j) {
        S3 o = cvt1(av[j]);
        xh[j] = o.h; xl[j] = o.l; xq[j] = o.q;
    }
}

#define GLDS(srcp, dstp) \
    __builtin_amdgcn_global_load_lds( \
        (const __attribute__((address_space(1))) void*)(srcp), \
        (__attribute__((address_space(3))) void*)(dstp), 16, 0, 0)

// ---------- kernel 0: W [64][4096] fp32 -> fragment-ordered bf16 terms -------
// Wf layout (float4 = bf16x8): [kstep 128][etile 4][term 3][lane 64]
__global__ void wpack(const float* __restrict__ W, float4* __restrict__ Wf,
                      float* __restrict__ out_counts) {
    const int l     = threadIdx.x;
    const int kstep = blockIdx.x;
    const int etile = blockIdx.y;
    if (kstep == 0 && etile == 0)
        out_counts[l] = 0.f;             // stream-ordered before router_finish
    const int e = etile * 16 + (l & 15);
    const int k = kstep * 32 + (l >> 4) * 8;
    const float* src = W + (size_t)e * K_DIM + k;
    bf16x8 h, l1, l2;
#pragma unroll
    for (int j = 0; j < 8; ++j) {
        S3 o = cvt1(src[j]);
        h[j] = o.h; l1[j] = o.l; l2[j] = o.q;
    }
    const size_t base = ((size_t)(kstep * 4 + etile) * 3) * 64 + l;
    Wf[base]       = __builtin_bit_cast(float4, h);
    Wf[base + 64]  = __builtin_bit_cast(float4, l1);
    Wf[base + 128] = __builtin_bit_cast(float4, l2);
}

// ---------- kernel 1: split-K GEMM — all-glds, DEPTH-3 ring pipeline ---------
// NO register-destined global loads anywhere in the K-loop (compiler-inserted
// waitcnt on reg loads + single vmcnt FIFO was re-serializing R5-R14). 4-slot
// LDS ring, 3 chunks in flight (~84 KB/CU); per-wave counted vmcnt; raw
// s_barrier x2 per chunk. KC=32 (1 MFMA kstep per chunk).
template <int NCH>
__global__ __launch_bounds__(512, 1) void gemm_mfma(
    const float*  __restrict__ x,
    const float4* __restrict__ Wf,
    float* __restrict__ P)          // [S][8192][64]
{
    static_assert(NCH >= 4, "ring needs >=4 chunks");
    __shared__ float4 xb[4][1024];   // x chunk: 128 rows x 8 f4 (swizzled) = 16 KB
    __shared__ float4 bb[4][768];    // B kstep: [et4][term3][lane64]       = 12 KB

    const int tid  = threadIdx.x;
    const int l    = tid & 63;
    const int wv   = __builtin_amdgcn_readfirstlane(tid >> 6);
    const int slice = blockIdx.x;
    const int t0    = blockIdx.y * TB;
    const int k0    = slice * (NCH * 32);

    const float4* x4 = (const float4*)x;
    // x staging: glds q covers LDS f4 idx q*512+tid -> row q*64+(tid>>3), slot tid&7
    // inverse swizzle: source col = (tid&7) ^ ((tid>>3)&7)
    const int xrow = tid >> 3;
    const int xcol = (tid & 7) ^ (xrow & 7);
    const size_t xs0 = (size_t)(t0 + xrow) * (K_DIM / 4) + (size_t)(k0 >> 2) + xcol;
    const size_t xs1 = xs0 + (size_t)64 * (K_DIM / 4);
    const int kb0 = k0 >> 5;               // first global kstep of this slice

    // A-read (swizzled): row r, slots s0=(l>>4)*2, s0+1; addr = r*8 + (s^(r&7))
    const int r   = wv * 16 + (l & 15);
    const int s0  = (l >> 4) * 2;
    const int rx7 = r & 7;
    const int ia0 = r * 8 + ((s0)     ^ rx7);
    const int ia1 = r * 8 + ((s0 + 1) ^ rx7);

    f32x4 acc[4];
#pragma unroll
    for (int et = 0; et < 4; ++et) acc[et] = (f32x4){0.f, 0.f, 0.f, 0.f};

    // per-chunk staging issue (wave-uniform dst bases, per-lane src)
#define STAGE(c)                                                                \
    do {                                                                        \
        const int rg = (c) & 3;                                                 \
        const size_t xo = (size_t)(c) * 8;                                      \
        GLDS(x4 + xs0 + xo, &xb[rg][0 * 512 + wv * 64]);                        \
        GLDS(x4 + xs1 + xo, &xb[rg][1 * 512 + wv * 64]);                        \
        const size_t bo = (size_t)(kb0 + (c)) * 768;                            \
        GLDS(Wf + bo + wv * 64 + l, &bb[rg][wv * 64]);                          \
        if (wv < 4)                                                             \
            GLDS(Wf + bo + 512 + wv * 64 + l, &bb[rg][512 + wv * 64]);          \
    } while (0)

    // prologue: 3 chunks in flight before first compute
    STAGE(0); STAGE(1); STAGE(2);

    for (int c = 0; c < NCH; ++c) {
        // barrier1: all waves done READING ring slot (c+3)&3 (== chunk c-1)
        __builtin_amdgcn_s_barrier();
        if (c + 3 < NCH) STAGE(c + 3);

        // counted wait for MY chunk-c loads; newer chunks stay in flight.
        // loads/chunk: wv<4 -> 4, wv>=4 -> 3.
        const int nb = (NCH - 1 - c < 3) ? (NCH - 1 - c) : 3;  // chunks beyond c
        if (wv < 4) {
            if      (nb == 3) asm volatile("s_waitcnt vmcnt(12)" ::: "memory");
            else if (nb == 2) asm volatile("s_waitcnt vmcnt(8)"  ::: "memory");
            else if (nb == 1) asm volatile("s_waitcnt vmcnt(4)"  ::: "memory");
            else              asm volatile("s_waitcnt vmcnt(0)"  ::: "memory");
        } else {
            if      (nb == 3) asm volatile("s_waitcnt vmcnt(9)"  ::: "memory");
            else if (nb == 2) asm volatile("s_waitcnt vmcnt(6)"  ::: "memory");
            else if (nb == 1) asm volatile("s_waitcnt vmcnt(3)"  ::: "memory");
            else              asm volatile("s_waitcnt vmcnt(0)"  ::: "memory");
        }
        // barrier2: every wave's chunk-c staging has landed in LDS
        __builtin_amdgcn_s_barrier();

        const int rg = c & 3;
        float4 a0 = xb[rg][ia0];
        float4 a1 = xb[rg][ia1];
        bf16x8 xh, xl, xq;
        cvt8(a0, a1, xh, xl, xq);

#pragma unroll
        for (int et = 0; et < 4; ++et) {
            const float4* bp = &bb[rg][et * 192 + l];
            bf16x8 wh = __builtin_bit_cast(bf16x8, bp[0]);
            bf16x8 wl = __builtin_bit_cast(bf16x8, bp[64]);
            bf16x8 wq = __builtin_bit_cast(bf16x8, bp[128]);
            acc[et] = __builtin_amdgcn_mfma_f32_16x16x32_bf16(xh, wh, acc[et], 0, 0, 0);
            acc[et] = __builtin_amdgcn_mfma_f32_16x16x32_bf16(xh, wl, acc[et], 0, 0, 0);
            acc[et] = __builtin_amdgcn_mfma_f32_16x16x32_bf16(xh, wq, acc[et], 0, 0, 0);
            acc[et] = __builtin_amdgcn_mfma_f32_16x16x32_bf16(xl, wh, acc[et], 0, 0, 0);
            acc[et] = __builtin_amdgcn_mfma_f32_16x16x32_bf16(xl, wl, acc[et], 0, 0, 0);
            acc[et] = __builtin_amdgcn_mfma_f32_16x16x32_bf16(xq, wh, acc[et], 0, 0, 0);
        }
    }
#undef STAGE

    // epilogue: C/D map col=lane&15 (expert), row=(lane>>4)*4+i (token)
    float* Pp = P + (size_t)slice * T_TOKENS * NEXP;
#pragma unroll
    for (int et = 0; et < 4; ++et) {
#pragma unroll
        for (int i = 0; i < 4; ++i) {
            int t = t0 + wv * 16 + (l >> 4) * 4 + i;
            Pp[(size_t)t * NEXP + et * 16 + (l & 15)] = acc[et][i];
        }
    }
}

// ---------- kernel 2: reduce slices + softmax + argmax + bincount ------------
template <int S>
__global__ __launch_bounds__(256) void router_finish_t(
    const float* __restrict__ P, float* __restrict__ out)
{
    const int lane = threadIdx.x & 63;   // expert
    const int wv   = threadIdx.x >> 6;
    const int t    = blockIdx.x * 4 + wv;

    float lg = 0.f;
#pragma unroll
    for (int s = 0; s < S; ++s)
        lg += P[((size_t)s * T_TOKENS + t) * NEXP + lane];

    float* out_w = out;
    float* out_i = out + T_TOKENS;
    float* out_s = out + 2 * T_TOKENS;
    float* out_c = out + 2 * T_TOKENS + (size_t)T_TOKENS * NEXP;

    float m = lg;
#pragma unroll
    for (int off = 32; off > 0; off >>= 1)
        m = fmaxf(m, __shfl_xor(m, off));
    float p = expf(lg - m);
    float s = p;
#pragma unroll
    for (int off = 32; off > 0; off >>= 1)
        s += __shfl_xor(s, off);
    float sc = p / s;

    float bv = sc; int bi = lane;
#pragma unroll
    for (int off = 32; off > 0; off >>= 1) {
        float ov = __shfl_xor(bv, off);
        int   oi = __shfl_xor(bi, off);
        if (ov > bv || (ov == bv && oi < bi)) { bv = ov; bi = oi; }
    }
    out_s[(size_t)t * NEXP + lane] = sc;
    if (lane == 0) {
        out_w[t] = bv;
        out_i[t] = (float)bi;
        atomicAdd(&out_c[bi], 1.0f);   // counts zeroed by wpack this call
    }
}

extern "C" void kernel_launch(void* const* d_in, const int* in_sizes, int n_in,
                              void* d_out, int out_size, void* d_ws, size_t ws_size,
                              hipStream_t stream)
{
    const float* x = (const float*)d_in[0];
    const float* W = (const float*)d_in[1];
    float* out = (float*)d_out;
    float* out_s = out + 2 * T_TOKENS;
    float* out_c = out + 2 * T_TOKENS + (size_t)T_TOKENS * NEXP;

    const size_t wf_bytes  = (size_t)128 * 4 * 3 * 64 * 16;           // 1.5 MiB
    const size_t per_slice = (size_t)T_TOKENS * NEXP * sizeof(float); // 2 MiB

    int S = 8;
    while (S > 1 && wf_bytes + (size_t)S * per_slice > ws_size) S >>= 1;
    float4* Wf = (float4*)d_ws;
    float* Pbuf;
    if (wf_bytes + per_slice <= ws_size) {
        Pbuf = (float*)((char*)d_ws + wf_bytes);
    } else {
        S = 1;
        Pbuf = out_s;
    }

    wpack<<<dim3(128, 4), 64, 0, stream>>>(W, Wf, out_c);
    switch (S) {
        case 8: gemm_mfma<16> <<<dim3(8, T_TOKENS / TB), 512, 0, stream>>>(x, Wf, Pbuf); break;
        case 4: gemm_mfma<32> <<<dim3(4, T_TOKENS / TB), 512, 0, stream>>>(x, Wf, Pbuf); break;
        case 2: gemm_mfma<64> <<<dim3(2, T_TOKENS / TB), 512, 0, stream>>>(x, Wf, Pbuf); break;
        default: gemm_mfma<128><<<dim3(1, T_TOKENS / TB), 512, 0, stream>>>(x, Wf, Pbuf); break;
    }
    switch (S) {
        case 8: router_finish_t<8><<<T_TOKENS / 4, 256, 0, stream>>>(Pbuf, out); break;
        case 4: router_finish_t<4><<<T_TOKENS / 4, 256, 0, stream>>>(Pbuf, out); break;
        case 2: router_finish_t<2><<<T_TOKENS / 4, 256, 0, stream>>>(Pbuf, out); break;
        default: router_finish_t<1><<<T_TOKENS / 4, 256, 0, stream>>>(Pbuf, out); break;
    }
}